// Round 1
// baseline (219.349 us; speedup 1.0000x reference)
//
#include <hip/hip_runtime.h>
#include <cmath>

// ConvLSTM fused per-step kernel.
// x: (B=8, T=16, C=16, H=128, W=128) f32
// Wx: (KH=4, KW=2, C=16, O=8) HWIO
// Wh: (4, 2, F=2, 8)
// out: (B, T, F, H, W) f32 — h for every step; also serves as h_prev input.
// ws: c-state buffer (B, F, H, W) f32 = 1 MB.

constexpr int B_ = 8;
constexpr int T_ = 16;
constexpr int C_ = 16;
constexpr int F_ = 2;
constexpr int O_ = 8;      // 4*F gate channels
constexpr int H_ = 128;
constexpr int W_ = 128;
constexpr int HW_ = H_ * W_;
constexpr int KH_ = 4;
constexpr int KW_ = 2;

__device__ __forceinline__ float hsig(float z) {
    return fminf(fmaxf(0.2f * z + 0.5f, 0.0f), 1.0f);
}

__global__ __launch_bounds__(256) void convlstm_step(
    const float* __restrict__ x,
    const float* __restrict__ Wx,
    const float* __restrict__ Wh,
    float* __restrict__ out,
    float* __restrict__ cbuf,
    int t)
{
    __shared__ float sWx[KH_ * KW_ * C_ * O_];   // 1024
    __shared__ float sWh[KH_ * KW_ * F_ * O_];   // 128

    for (int i = threadIdx.x; i < KH_ * KW_ * C_ * O_; i += 256) sWx[i] = Wx[i];
    for (int i = threadIdx.x; i < KH_ * KW_ * F_ * O_; i += 256) sWh[i] = Wh[i];
    __syncthreads();

    int gid = blockIdx.x * 256 + threadIdx.x;   // over B*H*W = 131072
    int b   = gid >> 14;                         // / 16384
    int pix = gid & (HW_ - 1);
    int oh  = pix >> 7;
    int ow  = pix & (W_ - 1);

    int trev = T_ - 1 - t;
    const float* xs = x + (size_t)(b * T_ + trev) * C_ * HW_;

    float acc[O_];
    #pragma unroll
    for (int o = 0; o < O_; ++o) acc[o] = 0.0f;

    bool cval = (ow + 1) < W_;     // kw=1 column valid
    int  co1  = cval ? 1 : 0;

    // ---- x-conv: SAME pad, KH=4 (pad_lo=1), KW=2 (pad_lo=0) ----
    #pragma unroll
    for (int kh = 0; kh < KH_; ++kh) {
        int ih   = oh + kh - 1;
        bool rv  = (unsigned)ih < (unsigned)H_;
        int ihc  = rv ? ih : 0;
        const float* xrow  = xs + ihc * W_ + ow;
        const float* xrow1 = xrow + co1;
        const float* wp = sWx + kh * (KW_ * C_ * O_);   // kh*256
        #pragma unroll
        for (int c = 0; c < C_; ++c) {
            float x0 = xrow[c * HW_];
            float x1 = xrow1[c * HW_];
            x0 = rv ? x0 : 0.0f;
            x1 = (rv && cval) ? x1 : 0.0f;
            #pragma unroll
            for (int o = 0; o < O_; ++o) {
                acc[o] = fmaf(x0, wp[c * O_ + o], acc[o]);
                acc[o] = fmaf(x1, wp[C_ * O_ + c * O_ + o], acc[o]);
            }
        }
    }

    // ---- h-conv (h_prev = out[b, t-1]); skipped at t==0 (h0 = 0) ----
    if (t > 0) {
        const float* hs = out + (size_t)(b * T_ + (t - 1)) * F_ * HW_;
        #pragma unroll
        for (int kh = 0; kh < KH_; ++kh) {
            int ih   = oh + kh - 1;
            bool rv  = (unsigned)ih < (unsigned)H_;
            int ihc  = rv ? ih : 0;
            const float* hrow  = hs + ihc * W_ + ow;
            const float* hrow1 = hrow + co1;
            const float* wp = sWh + kh * (KW_ * F_ * O_);   // kh*32
            #pragma unroll
            for (int f = 0; f < F_; ++f) {
                float h0 = hrow[f * HW_];
                float h1 = hrow1[f * HW_];
                h0 = rv ? h0 : 0.0f;
                h1 = (rv && cval) ? h1 : 0.0f;
                #pragma unroll
                for (int o = 0; o < O_; ++o) {
                    acc[o] = fmaf(h0, wp[f * O_ + o], acc[o]);
                    acc[o] = fmaf(h1, wp[F_ * O_ + f * O_ + o], acc[o]);
                }
            }
        }
    }

    // ---- gates + state update ----
    // channel groups: [0,1]=i, [2,3]=f, [4,5]=g(cell), [6,7]=o
    size_t cidx = (size_t)b * F_ * HW_ + pix;
    float cp0 = 0.0f, cp1 = 0.0f;
    if (t > 0) { cp0 = cbuf[cidx]; cp1 = cbuf[cidx + HW_]; }

    float gi0 = hsig(acc[0]);
    float gi1 = hsig(acc[1]);
    float gf0 = hsig(acc[2]);
    float gf1 = hsig(acc[3]);
    float gg0 = tanhf(acc[4]);
    float gg1 = tanhf(acc[5]);
    float go0 = hsig(acc[6]);
    float go1 = hsig(acc[7]);

    float cn0 = gf0 * cp0 + gi0 * gg0;
    float cn1 = gf1 * cp1 + gi1 * gg1;
    cbuf[cidx]       = cn0;
    cbuf[cidx + HW_] = cn1;

    size_t oidx = (size_t)(b * T_ + t) * F_ * HW_ + pix;
    out[oidx]       = go0 * tanhf(cn0);
    out[oidx + HW_] = go1 * tanhf(cn1);
}

extern "C" void kernel_launch(void* const* d_in, const int* in_sizes, int n_in,
                              void* d_out, int out_size, void* d_ws, size_t ws_size,
                              hipStream_t stream) {
    const float* x  = (const float*)d_in[0];
    const float* Wx = (const float*)d_in[1];
    const float* Wh = (const float*)d_in[2];
    float* out  = (float*)d_out;
    float* cbuf = (float*)d_ws;   // B*F*HW floats = 1 MB

    int blocks = (B_ * HW_) / 256;   // 512
    for (int t = 0; t < T_; ++t) {
        convlstm_step<<<blocks, 256, 0, stream>>>(x, Wx, Wh, out, cbuf, t);
    }
}